// Round 13
// baseline (167.178 us; speedup 1.0000x reference)
//
#include <hip/hip_runtime.h>

typedef float f4 __attribute__((ext_vector_type(4)));

#define LOG2E 1.44269504f
#define LN2 0.69314718f
#define DEADD (1 << 28)
#define RS2 66   // ring line stride in uint2

__device__ __forceinline__ float sumsq_fp8x4(unsigned int pk) {
  float d0 = __builtin_amdgcn_cvt_f32_fp8((int)pk, 0);
  float d1 = __builtin_amdgcn_cvt_f32_fp8((int)pk, 1);
  float d2 = __builtin_amdgcn_cvt_f32_fp8((int)pk, 2);
  float d3 = __builtin_amdgcn_cvt_f32_fp8((int)pk, 3);
  return (d0 * d0 + d1 * d1) + (d2 * d2 + d3 * d3);
}

// exp-domain DP cell (R8-verified): value 2^-V = E * 2^-d, E in [0.5,1). All full-rate VALU.
__device__ __forceinline__ void cellf(float& Eo, int& don,
                                      float EL, int dL, float ED, int dD,
                                      float EU, int dU, float m, int ci126) {
  int ref = min(min(dL, dD), dU);
  float S = ldexpf(EL, ref - dL) + ldexpf(ED, ref - dD) + ldexpf(EU, ref - dU);
  float v = m * S;
  unsigned int u = __builtin_bit_cast(unsigned int, v);
  Eo = __builtin_bit_cast(float, (u & 0x007FFFFFu) | 0x3F000000u);
  don = (ref + ci126) - (int)(u >> 23);
}

// Wave-specialized: wave0 = producer (fp8 MFMA -> (m,ci) ring), wave1 = consumer
// (ldexp exp-domain DP, 4 rows/lane). 2-key windows, ~40 barriers total.
__global__ __launch_bounds__(128)
void sdtw_ws(const float* __restrict__ X, const float* __restrict__ Y,
             float* __restrict__ out) {
  const int p = blockIdx.x;
  const int type = p >> 9;            // 0: xy, 1: xx, 2: yy
  const int b = p & 511;
  const float* Ap = (type == 2 ? Y : X) + (size_t)b * 256 * 64;
  const float* Bp = (type == 1 ? X : Y) + (size_t)b * 256 * 64;
  const float wgt = (type == 0) ? (LN2 / 512.0f) : (-LN2 / 1024.0f);

  __shared__ uint2 ring[32 * RS2];          // {fp8x4 m, u8x4 ci} per (line, row-quad) 16896 B
  __shared__ unsigned int sB[4096];         // fp8 B rows, swizzled                   16384 B
  __shared__ _Float16 saa[256];             // 0.5*log2e*||q(A_r)||^2                   512 B
  __shared__ _Float16 sbb[256];             //                                          512 B

  const int tid = threadIdx.x;
  const int wv = tid >> 6;
  const int lane = tid & 63;
  const int hk = lane >> 4, lr = lane & 15;
  const int bpaddr = ((lane + 63) & 63) << 2;

  // ---- zero-init ring: stale/warm-up reads must decode dead (m=0,ci=0) ----
  #pragma unroll 1
  for (int i = 0; i < 17; ++i) {
    int idx = i * 128 + tid;
    if (idx < 32 * RS2) ring[idx] = make_uint2(0u, 0u);
  }

  // ---- stage B -> fp8 LDS (swizzled) + quantized row norms (both waves) ----
  {
    const float4* B4 = (const float4*)Bp;
    const int q = tid & 15;
    #pragma unroll 1
    for (int it = 0; it < 32; ++it) {
      int pidx = it * 128 + tid;
      int row = pidx >> 4;
      float4 v = B4[pidx];
      unsigned int pk = __builtin_amdgcn_cvt_pk_fp8_f32(v.x, v.y, 0, false);
      pk = __builtin_amdgcn_cvt_pk_fp8_f32(v.z, v.w, pk, true);
      sB[row * 16 + (q ^ ((row & 7) << 1))] = pk;
      float pr = sumsq_fp8x4(pk);
      pr += __shfl_xor(pr, 1);
      pr += __shfl_xor(pr, 2);
      pr += __shfl_xor(pr, 4);
      pr += __shfl_xor(pr, 8);
      if (q == 0) sbb[row] = (_Float16)(0.5f * LOG2E * pr);
    }
  }

  // ---- producer-only: A fragments -> fp8 registers + row norms ----
  uint2 af[16][2];
  if (wv == 0) {
    #pragma unroll
    for (int Rt = 0; Rt < 16; ++Rt) {
      float nrm = 0.f;
      #pragma unroll
      for (int kk = 0; kk < 2; ++kk) {
        const float4* src = (const float4*)(Ap + (Rt * 16 + lr) * 64 + kk * 32 + hk * 8);
        float4 x = src[0], y = src[1];
        unsigned int p0 = __builtin_amdgcn_cvt_pk_fp8_f32(x.x, x.y, 0, false);
        p0 = __builtin_amdgcn_cvt_pk_fp8_f32(x.z, x.w, p0, true);
        unsigned int p1 = __builtin_amdgcn_cvt_pk_fp8_f32(y.x, y.y, 0, false);
        p1 = __builtin_amdgcn_cvt_pk_fp8_f32(y.z, y.w, p1, true);
        af[Rt][kk] = make_uint2(p0, p1);
        nrm += sumsq_fp8x4(p0) + sumsq_fp8x4(p1);
      }
      nrm += __shfl_xor(nrm, 16);
      nrm += __shfl_xor(nrm, 32);
      if (hk == 0) saa[Rt * 16 + lr] = (_Float16)(0.5f * LOG2E * nrm);
    }
  }
  __syncthreads();

  // ---- produce one tile: Rt compile-time, Ct runtime; output (m, ci) ----
  #define PRODUCE_TILE(RT, CT)                                                     \
    {                                                                              \
      int n_ = (CT) * 16 + lr;                                                     \
      int sw_ = n_ & 7;                                                            \
      uint2 b0_ = *(const uint2*)&sB[n_ * 16 + 2 * (hk ^ sw_)];                    \
      uint2 b1_ = *(const uint2*)&sB[n_ * 16 + 2 * ((hk + 4) ^ sw_)];              \
      f4 acc_ = {0.f, 0.f, 0.f, 0.f};                                              \
      acc_ = __builtin_amdgcn_mfma_f32_16x16x32_fp8_fp8(                           \
               __builtin_bit_cast(long, af[RT][0]), __builtin_bit_cast(long, b0_), \
               acc_, 0, 0, 0);                                                     \
      acc_ = __builtin_amdgcn_mfma_f32_16x16x32_fp8_fp8(                           \
               __builtin_bit_cast(long, af[RT][1]), __builtin_bit_cast(long, b1_), \
               acc_, 0, 0, 0);                                                     \
      int r0_ = (RT) * 16 + hk * 4;                                                \
      float bbv_ = (float)sbb[n_];                                                 \
      float c0_ = fminf(fmaxf(fmaf(-LOG2E, acc_.x, (float)saa[r0_ + 0] + bbv_), 0.f), 254.0f); \
      float c1_ = fminf(fmaxf(fmaf(-LOG2E, acc_.y, (float)saa[r0_ + 1] + bbv_), 0.f), 254.0f); \
      float c2_ = fminf(fmaxf(fmaf(-LOG2E, acc_.z, (float)saa[r0_ + 2] + bbv_), 0.f), 254.0f); \
      float c3_ = fminf(fmaxf(fmaf(-LOG2E, acc_.w, (float)saa[r0_ + 3] + bbv_), 0.f), 254.0f); \
      float f0_ = truncf(c0_), f1_ = truncf(c1_), f2_ = truncf(c2_), f3_ = truncf(c3_); \
      float x0_ = c0_ - f0_, x1_ = c1_ - f1_, x2_ = c2_ - f2_, x3_ = c3_ - f3_;    \
      float m0_ = fmaf(x0_, fmaf(x0_, 0.17157f, -0.67157f), 1.0f);                 \
      float m1_ = fmaf(x1_, fmaf(x1_, 0.17157f, -0.67157f), 1.0f);                 \
      float m2_ = fmaf(x2_, fmaf(x2_, 0.17157f, -0.67157f), 1.0f);                 \
      float m3_ = fmaf(x3_, fmaf(x3_, 0.17157f, -0.67157f), 1.0f);                 \
      int pkm_ = __builtin_amdgcn_cvt_pk_fp8_f32(m0_, m1_, 0, false);              \
      pkm_ = __builtin_amdgcn_cvt_pk_fp8_f32(m2_, m3_, pkm_, true);                \
      unsigned int pkc_ = (unsigned int)f0_ | ((unsigned int)f1_ << 8)             \
                        | ((unsigned int)f2_ << 16) | ((unsigned int)f3_ << 24);   \
      int tr_ = 4 * (RT) + hk;                                                     \
      int s1_ = n_ + tr_;                                                          \
      ring[(s1_ & 31) * RS2 + tr_] = make_uint2((unsigned int)pkm_, pkc_);         \
    }

  // ---- consumer DP state (exp domain, R8-verified) ----
  float E1 = 0.f, E2 = 0.f, E3 = 0.f, E4 = 0.f;
  int d1 = DEADD, d2 = DEADD, d3 = DEADD, d4 = DEADD;
  float dgE = (lane == 0) ? 1.0f : 0.f;   // V[0][0]=0 -> (1,0)
  int dgd = (lane == 0) ? 0 : DEADD;

  #define DP_STEP(W)                                                               \
    {                                                                              \
      float upE = __builtin_bit_cast(float,                                        \
          __builtin_amdgcn_ds_bpermute(bpaddr, __builtin_bit_cast(int, E4)));      \
      int upd = __builtin_amdgcn_ds_bpermute(bpaddr, d4);                          \
      if (lane == 0) { upE = 0.f; upd = DEADD; }                                   \
      float m0 = __builtin_amdgcn_cvt_f32_fp8((int)(W).x, 0);                      \
      float m1 = __builtin_amdgcn_cvt_f32_fp8((int)(W).x, 1);                      \
      float m2 = __builtin_amdgcn_cvt_f32_fp8((int)(W).x, 2);                      \
      float m3 = __builtin_amdgcn_cvt_f32_fp8((int)(W).x, 3);                      \
      int c0 = (int)((W).y & 255u) + 126;                                          \
      int c1 = (int)(((W).y >> 8) & 255u) + 126;                                   \
      int c2 = (int)(((W).y >> 16) & 255u) + 126;                                  \
      int c3 = (int)((W).y >> 24) + 126;                                           \
      float v1E, v2E, v3E, v4E; int v1d, v2d, v3d, v4d;                            \
      cellf(v1E, v1d, E1, d1, dgE, dgd, upE, upd, m0, c0);                         \
      cellf(v2E, v2d, E2, d2, E1, d1, v1E, v1d, m1, c1);                           \
      cellf(v3E, v3d, E3, d3, E2, d2, v2E, v2d, m2, c2);                           \
      cellf(v4E, v4d, E4, d4, E3, d3, v3E, v3d, m3, c3);                           \
      E1 = v1E; d1 = v1d; E2 = v2E; d2 = v2d;                                      \
      E3 = v3E; d3 = v3d; E4 = v4E; d4 = v4d;                                      \
      dgE = upE; dgd = upd;                                                        \
    }

  #define CONSUME8(L0)                                                             \
    {                                                                              \
      uint2 w0 = ring[(((L0) + 0) & 31) * RS2 + lane];                             \
      uint2 w1 = ring[(((L0) + 1) & 31) * RS2 + lane];                             \
      uint2 w2 = ring[(((L0) + 2) & 31) * RS2 + lane];                             \
      uint2 w3 = ring[(((L0) + 3) & 31) * RS2 + lane];                             \
      uint2 w4 = ring[(((L0) + 4) & 31) * RS2 + lane];                             \
      uint2 w5 = ring[(((L0) + 5) & 31) * RS2 + lane];                             \
      uint2 w6 = ring[(((L0) + 6) & 31) * RS2 + lane];                             \
      uint2 w7 = ring[(((L0) + 7) & 31) * RS2 + lane];                             \
      DP_STEP(w0) DP_STEP(w1) DP_STEP(w2) DP_STEP(w3)                              \
      DP_STEP(w4) DP_STEP(w5) DP_STEP(w6) DP_STEP(w7)                              \
    }

  // ---- prologue: produce keys 0,1 (tiles (0,0),(1,0)) ----
  if (wv == 0) {
    PRODUCE_TILE(0, 0)
    PRODUCE_TILE(1, 0)
  }
  __syncthreads();

  // ---- main: 19 iterations x 2 sub-windows (2 keys each) ----
  #pragma unroll 1
  for (int hh = 0; hh < 19; ++hh) {
    // sub-window A: produce keys 4hh+2 (r=2), 4hh+3 (r=3); consume lines 16hh..16hh+7
    if (wv == 0) {
      #pragma unroll
      for (int dlt = 0; dlt < 4; ++dlt) {
        int Ct = hh - dlt;
        if (Ct >= 0 && Ct <= 15) {
          PRODUCE_TILE(2 + 4 * dlt, Ct)
          PRODUCE_TILE(3 + 4 * dlt, Ct)
        }
      }
    } else {
      CONSUME8(16 * hh)
    }
    __syncthreads();
    // sub-window B: produce keys 4hh+4 (r=0), 4hh+5 (r=1); consume lines 16hh+8..16hh+15
    if (wv == 0) {
      if (hh < 18) {
        #pragma unroll
        for (int dlt = 0; dlt < 4; ++dlt) {
          int Ct = hh + 1 - dlt;
          if (Ct >= 0 && Ct <= 15) {
            PRODUCE_TILE(0 + 4 * dlt, Ct)
            PRODUCE_TILE(1 + 4 * dlt, Ct)
          }
        }
      }
    } else {
      CONSUME8(16 * hh + 8)
    }
    __syncthreads();
  }

  // ---- consumer tail: lines 304..318 ----
  if (wv == 1) {
    #pragma unroll 1
    for (int u = 0; u < 15; ++u) {
      uint2 cw = ring[((304 + u) & 31) * RS2 + lane];
      DP_STEP(cw)
    }
    // lane 63 holds V[256][256]: V = d - log2(E) (log2 domain)
    if (lane == 63) atomicAdd(out, wgt * ((float)d4 - __log2f(E4)));
  }
}

extern "C" void kernel_launch(void* const* d_in, const int* in_sizes, int n_in,
                              void* d_out, int out_size, void* d_ws, size_t ws_size,
                              hipStream_t stream) {
  const float* X = (const float*)d_in[0];
  const float* Y = (const float*)d_in[1];
  float* out = (float*)d_out;
  hipMemsetAsync(out, 0, sizeof(float) * out_size, stream);
  sdtw_ws<<<1536, 128, 0, stream>>>(X, Y, out);
}